// Round 4
// baseline (326.748 us; speedup 1.0000x reference)
//
#include <hip/hip_runtime.h>
#include <hip/hip_bf16.h>
#include <hip/hip_cooperative_groups.h>
#include <math.h>

namespace cg = cooperative_groups;

// Problem constants (B,D,N from reference)
#define MDIM 4096   // batch rows
#define KDIM 2048   // feature dim D
#define NDIM 4096   // output dim N
#define DT   0.01f
#define TWO_PI_F 6.283185307179586f
#define CH 64       // scan chunks
#define CL 64       // steps per chunk  (CH*CL == MDIM)

typedef __attribute__((ext_vector_type(8))) short bf16x8;
typedef __attribute__((ext_vector_type(4))) float f32x4;

__device__ __forceinline__ unsigned short f2bf(float f) {
  unsigned int u = __float_as_uint(f);
  u += 0x7FFFu + ((u >> 16) & 1u);           // round-to-nearest-even
  return (unsigned short)(u >> 16);
}
__device__ __forceinline__ float bf2f(unsigned short u) {
  return __uint_as_float(((unsigned int)u) << 16);
}

// -------- fused cast fp32 -> bf16 for x and W (both 8M floats) --------
__global__ void cast2_bf16_kernel(const float* __restrict__ s0,
                                  unsigned short* __restrict__ d0,
                                  const float* __restrict__ s1,
                                  unsigned short* __restrict__ d1,
                                  int n4each) {
  int i = blockIdx.x * blockDim.x + threadIdx.x;
  const float4* sp;
  ushort4* dp;
  int j;
  if (i < n4each) { sp = (const float4*)s0; dp = (ushort4*)d0; j = i; }
  else            { sp = (const float4*)s1; dp = (ushort4*)d1; j = i - n4each; }
  float4 v = sp[j];
  ushort4 o;
  o.x = f2bf(v.x); o.y = f2bf(v.y); o.z = f2bf(v.z); o.w = f2bf(v.w);
  dp[j] = o;
}

// ---------------- GEMM: force = x @ W^T + b, bf16 MFMA ----------------
// Round-2 version (manual register staging, measured 90.6-92.0 us; the
// global_load_lds variant measured 92.3-93.3 -> reverted).
__global__ __launch_bounds__(256, 2) void gemm_bt_kernel(
    const unsigned short* __restrict__ A,
    const unsigned short* __restrict__ Bm,
    const float* __restrict__ bias,
    unsigned short* __restrict__ C) {
  __shared__ __align__(16) unsigned short sA[128 * 32];
  __shared__ __align__(16) unsigned short sB[128 * 32];

  const int tid  = threadIdx.x;
  const int lane = tid & 63;
  const int wave = tid >> 6;
  const int wr = wave >> 1;        // wave row (0..1) -> 64 rows
  const int wc = wave & 1;         // wave col (0..1) -> 64 cols
  const int q  = lane >> 4;        // quad 0..3
  const int lm = lane & 15;

  const int bM = blockIdx.x * 128;
  const int bN = blockIdx.y * 128;

  f32x4 acc[4][4];
#pragma unroll
  for (int i = 0; i < 4; i++)
#pragma unroll
    for (int j = 0; j < 4; j++) acc[i][j] = (f32x4){0.f, 0.f, 0.f, 0.f};

  // staging: 128x32 bf16 tile = 8KB = 512 x 16B; 256 threads -> 2 slots each
  const int idx0 = tid;            // rows 0..63
  const int idx1 = tid + 256;      // rows 64..127
  const int r0 = idx0 >> 2, c0 = (idx0 & 3) * 8;
  const int r1 = idx1 >> 2, c1 = (idx1 & 3) * 8;

  for (int k0 = 0; k0 < KDIM; k0 += 32) {
    uint4 av0 = *(const uint4*)&A [(size_t)(bM + r0) * KDIM + k0 + c0];
    uint4 av1 = *(const uint4*)&A [(size_t)(bM + r1) * KDIM + k0 + c1];
    uint4 bv0 = *(const uint4*)&Bm[(size_t)(bN + r0) * KDIM + k0 + c0];
    uint4 bv1 = *(const uint4*)&Bm[(size_t)(bN + r1) * KDIM + k0 + c1];
    __syncthreads();               // previous iter's LDS reads complete
    *(uint4*)&sA[idx0 * 8] = av0;
    *(uint4*)&sA[idx1 * 8] = av1;
    *(uint4*)&sB[idx0 * 8] = bv0;
    *(uint4*)&sB[idx1 * 8] = bv1;
    __syncthreads();               // LDS tile visible

    bf16x8 af[4], bfr[4];
#pragma unroll
    for (int mt = 0; mt < 4; mt++)
      af[mt]  = *(const bf16x8*)&sA[(wr * 64 + mt * 16 + lm) * 32 + q * 8];
#pragma unroll
    for (int nt = 0; nt < 4; nt++)
      bfr[nt] = *(const bf16x8*)&sB[(wc * 64 + nt * 16 + lm) * 32 + q * 8];

#pragma unroll
    for (int mt = 0; mt < 4; mt++)
#pragma unroll
      for (int nt = 0; nt < 4; nt++)
        acc[mt][nt] = __builtin_amdgcn_mfma_f32_16x16x32_bf16(
            af[mt], bfr[nt], acc[mt][nt], 0, 0, 0);
  }

  // epilogue: D layout col=lane&15, row=quad*4+reg (m89/m91-verified)
#pragma unroll
  for (int nt = 0; nt < 4; nt++) {
    const int col = bN + wc * 64 + nt * 16 + lm;
    const float bz = bias[col];
#pragma unroll
    for (int mt = 0; mt < 4; mt++) {
      const int row0 = bM + wr * 64 + mt * 16 + q * 4;
#pragma unroll
      for (int r = 0; r < 4; r++)
        C[(size_t)(row0 + r) * NDIM + col] = f2bf(acc[mt][nt][r] + bz);
    }
  }
}

// ---------------- fused scan: pass1 + pass2 + pass3, cooperative ----------
// Block = (chunk c, 512-column group). Force tile staged to LDS once; chunk
// partials -> grid.sync -> per-block carry lookback -> replay from LDS.
// 64 KB LDS -> exactly 2 blocks/CU; grid 512 = 2*256 co-resident.
__global__ __launch_bounds__(256, 2) void scan_fused(
    const unsigned short* __restrict__ force,
    const float* __restrict__ amp,
    const float* __restrict__ freq,
    const float* __restrict__ phase,
    const float* __restrict__ damp,
    float* __restrict__ chunkS,
    float* __restrict__ chunkV,
    float* __restrict__ out) {
  __shared__ __align__(16) unsigned short sF[CL * 512];   // 64 KB

  const int tid = threadIdx.x;
  const int c = blockIdx.x >> 3;                 // chunk 0..63
  const int colBase = (blockIdx.x & 7) * 512;

  // ---- phase A: stage 64x512 bf16 force tile (coalesced 16B/lane) ----
#pragma unroll
  for (int k = 0; k < 16; k++) {
    int slot = tid + 256 * k;                    // 0..4095
    *(uint4*)&sF[slot * 8] =
        *(const uint4*)&force[((size_t)c * CL + (slot >> 6)) * NDIM +
                              colBase + (slot & 63) * 8];
  }
  __syncthreads();

  const int n = colBase + tid * 2;               // 2 columns per thread
  float2 fr = *(const float2*)&freq[n];
  float2 dv = *(const float2*)&damp[n];
  const float om0 = TWO_PI_F * fr.x, om1 = TWO_PI_F * fr.y;
  const float osq0 = om0 * om0,      osq1 = om1 * om1;
  const float dp0 = dv.x,            dp1 = dv.y;

  // pass1: zero-init chunk partial
  float s0 = 0.f, v0 = 0.f, s1 = 0.f, v1 = 0.f;
#pragma unroll 8
  for (int i = 0; i < CL; i++) {
    ushort2 f2 = *(const ushort2*)&sF[i * 512 + tid * 2];
    float f0 = bf2f(f2.x), f1 = bf2f(f2.y);
    v0 += (-osq0 * s0 - dp0 * v0 + f0) * DT;  s0 += v0 * DT;
    v1 += (-osq1 * s1 - dp1 * v1 + f1) * DT;  s1 += v1 * DT;
  }
  *(float2*)&chunkS[c * NDIM + n] = make_float2(s0, s1);
  *(float2*)&chunkV[c * NDIM + n] = make_float2(v0, v1);
  __threadfence();
  cg::this_grid().sync();

  // ---- phase B: M^64 lookback over earlier chunks (same math as pass2) ----
  float p00 = 1.f - osq0 * DT * DT, p01 = DT * (1.f - dp0 * DT);
  float p10 = -osq0 * DT,           p11 = 1.f - dp0 * DT;
  float q00 = 1.f - osq1 * DT * DT, q01 = DT * (1.f - dp1 * DT);
  float q10 = -osq1 * DT,           q11 = 1.f - dp1 * DT;
#pragma unroll
  for (int i = 0; i < 6; i++) {
    float b00 = p00 * p00 + p01 * p10, b01 = p00 * p01 + p01 * p11;
    float b10 = p10 * p00 + p11 * p10, b11 = p10 * p01 + p11 * p11;
    p00 = b00; p01 = b01; p10 = b10; p11 = b11;
    float d00 = q00 * q00 + q01 * q10, d01 = q00 * q01 + q01 * q11;
    float d10 = q10 * q00 + q11 * q10, d11 = q10 * q01 + q11 * q11;
    q00 = d00; q01 = d01; q10 = d10; q11 = d11;
  }
  float cs0 = 0.f, cv0 = 0.f, cs1 = 0.f, cv1 = 0.f;
  for (int cc = 0; cc < c; cc++) {
    float2 ls = *(const float2*)&chunkS[cc * NDIM + n];
    float2 lv = *(const float2*)&chunkV[cc * NDIM + n];
    float t0 = p00 * cs0 + p01 * cv0 + ls.x;
    float u0 = p10 * cs0 + p11 * cv0 + lv.x;
    cs0 = t0; cv0 = u0;
    float t1 = q00 * cs1 + q01 * cv1 + ls.y;
    float u1 = q10 * cs1 + q11 * cv1 + lv.y;
    cs1 = t1; cv1 = u1;
  }

  // ---- phase C: replay from LDS with carry, osc + clip, fp32 out ----
  float2 am = *(const float2*)&amp[n];
  float2 ph = *(const float2*)&phase[n];
  const float osc0 = am.x * sinf(om0 * DT + ph.x);   // t = DT
  const float osc1 = am.y * sinf(om1 * DT + ph.y);
  s0 = cs0; v0 = cv0; s1 = cs1; v1 = cv1;
#pragma unroll 8
  for (int i = 0; i < CL; i++) {
    ushort2 f2 = *(const ushort2*)&sF[i * 512 + tid * 2];
    float f0 = bf2f(f2.x), f1 = bf2f(f2.y);
    v0 += (-osq0 * s0 - dp0 * v0 + f0) * DT;  s0 += v0 * DT;
    v1 += (-osq1 * s1 - dp1 * v1 + f1) * DT;  s1 += v1 * DT;
    float o0 = fminf(1.f, fmaxf(-1.f, s0 + osc0));
    float o1 = fminf(1.f, fmaxf(-1.f, s1 + osc1));
    *(float2*)&out[((size_t)c * CL + i) * NDIM + n] = make_float2(o0, o1);
  }
}

// ---------------- launch ----------------
extern "C" void kernel_launch(void* const* d_in, const int* in_sizes, int n_in,
                              void* d_out, int out_size, void* d_ws, size_t ws_size,
                              hipStream_t stream) {
  const float* x     = (const float*)d_in[0];
  const float* W     = (const float*)d_in[1];
  const float* bias  = (const float*)d_in[2];
  const float* amp   = (const float*)d_in[3];
  const float* freq  = (const float*)d_in[4];
  const float* phase = (const float*)d_in[5];
  const float* damp  = (const float*)d_in[6];

  // workspace layout (peak 64 MiB):
  //   [0,16Mi)   xbf  (chunkS/V alias this region after GEMM consumes it)
  //   [16,32Mi)  wbf
  //   [32,64Mi)  force bf16
  unsigned short* xbf   = (unsigned short*)d_ws;
  unsigned short* wbf   = xbf + (size_t)MDIM * KDIM;
  unsigned short* force = wbf + (size_t)NDIM * KDIM;
  float* chunkS = (float*)d_ws;            // aliases xbf: dead after GEMM
  float* chunkV = chunkS + CH * NDIM;
  float* outp   = (float*)d_out;

  const int n4each = MDIM * KDIM / 4;      // == NDIM*KDIM/4 (both 8M floats)
  cast2_bf16_kernel<<<(2 * n4each + 255) / 256, 256, 0, stream>>>(
      x, xbf, W, wbf, n4each);

  dim3 gg(MDIM / 128, NDIM / 128);
  gemm_bt_kernel<<<gg, 256, 0, stream>>>(xbf, wbf, bias, force);

  void* args[] = {(void*)&force, (void*)&amp, (void*)&freq, (void*)&phase,
                  (void*)&damp, (void*)&chunkS, (void*)&chunkV, (void*)&outp};
  hipLaunchCooperativeKernel((const void*)scan_fused, dim3(CH * 8), dim3(256),
                             args, 0, stream);
}

// Round 5
// 250.821 us; speedup vs baseline: 1.3027x; 1.3027x over previous
//
#include <hip/hip_runtime.h>
#include <hip/hip_bf16.h>
#include <math.h>

// Problem constants (B,D,N from reference)
#define MDIM 4096   // batch rows
#define KDIM 2048   // feature dim D
#define NDIM 4096   // output dim N
#define DT   0.01f
#define TWO_PI_F 6.283185307179586f
#define CH 64       // scan chunks (MDIM/CL)
#define CL 64       // steps per chunk

typedef __attribute__((ext_vector_type(8))) short bf16x8;
typedef __attribute__((ext_vector_type(4))) float f32x4;

__device__ __forceinline__ unsigned short f2bf(float f) {
  unsigned int u = __float_as_uint(f);
  u += 0x7FFFu + ((u >> 16) & 1u);           // round-to-nearest-even
  return (unsigned short)(u >> 16);
}
__device__ __forceinline__ float bf2f(unsigned short u) {
  return __uint_as_float(((unsigned int)u) << 16);
}
// packed fp32 pair -> bf16 pair (v_cvt_pk_bf16_f32 on gfx950)
__device__ __forceinline__ unsigned int pk2(float lo, float hi) {
  __hip_bfloat162 h = __float22bfloat162_rn(make_float2(lo, hi));
  return *(unsigned int*)&h;                 // .x in low 16 bits
}

// ======== kernel 1: GEMM (fp32 in, bf16 MFMA) + fused chunk scan ========
// force = x @ W^T + b computed 128x128/block; epilogue per wave:
//   - scatter C-layout tile to row-major LDS (bf16, bias added)
//   - lane n scans column n (64 rows, zero init) -> zpart (bf16) + partials
__global__ __launch_bounds__(256, 2) void gemm_scan_kernel(
    const float* __restrict__ A,       // x  [MDIM][KDIM] fp32
    const float* __restrict__ Bm,      // W  [NDIM][KDIM] fp32
    const float* __restrict__ bias,
    const float* __restrict__ freq,
    const float* __restrict__ damp,
    unsigned short* __restrict__ zpart,   // [MDIM][NDIM] bf16 zero-init states
    float* __restrict__ chunkS,           // [CH][NDIM]
    float* __restrict__ chunkV) {
  __shared__ __align__(16) unsigned short smem[16384];   // 32 KB
  unsigned short* sA = smem;          // [128*32] staging
  unsigned short* sB = smem + 4096;   // [128*32] staging

  const int tid  = threadIdx.x;
  const int lane = tid & 63;
  const int wave = tid >> 6;
  const int wr = wave >> 1;        // wave row (0..1) -> 64 rows (= one chunk)
  const int wc = wave & 1;         // wave col (0..1) -> 64 cols
  const int q  = lane >> 4;        // quad 0..3
  const int lm = lane & 15;

  const int bM = blockIdx.x * 128;
  const int bN = blockIdx.y * 128;

  f32x4 acc[4][4];
#pragma unroll
  for (int i = 0; i < 4; i++)
#pragma unroll
    for (int j = 0; j < 4; j++) acc[i][j] = (f32x4){0.f, 0.f, 0.f, 0.f};

  // staging: 128x32 tile; slot = 8 elems; 512 slots; 2 slots/thread
  const int idx0 = tid;            // rows 0..63
  const int idx1 = tid + 256;      // rows 64..127
  const int r0 = idx0 >> 2, c0 = (idx0 & 3) * 8;
  const int r1 = idx1 >> 2, c1 = (idx1 & 3) * 8;
  const float* gA0 = A  + (size_t)(bM + r0) * KDIM + c0;
  const float* gA1 = A  + (size_t)(bM + r1) * KDIM + c1;
  const float* gB0 = Bm + (size_t)(bN + r0) * KDIM + c0;
  const float* gB1 = Bm + (size_t)(bN + r1) * KDIM + c1;

  for (int k0 = 0; k0 < KDIM; k0 += 32) {
    float4 aL0 = *(const float4*)(gA0 + k0);
    float4 aH0 = *(const float4*)(gA0 + k0 + 4);
    float4 aL1 = *(const float4*)(gA1 + k0);
    float4 aH1 = *(const float4*)(gA1 + k0 + 4);
    float4 bL0 = *(const float4*)(gB0 + k0);
    float4 bH0 = *(const float4*)(gB0 + k0 + 4);
    float4 bL1 = *(const float4*)(gB1 + k0);
    float4 bH1 = *(const float4*)(gB1 + k0 + 4);
    uint4 av0 = {pk2(aL0.x,aL0.y), pk2(aL0.z,aL0.w), pk2(aH0.x,aH0.y), pk2(aH0.z,aH0.w)};
    uint4 av1 = {pk2(aL1.x,aL1.y), pk2(aL1.z,aL1.w), pk2(aH1.x,aH1.y), pk2(aH1.z,aH1.w)};
    uint4 bv0 = {pk2(bL0.x,bL0.y), pk2(bL0.z,bL0.w), pk2(bH0.x,bH0.y), pk2(bH0.z,bH0.w)};
    uint4 bv1 = {pk2(bL1.x,bL1.y), pk2(bL1.z,bL1.w), pk2(bH1.x,bH1.y), pk2(bH1.z,bH1.w)};
    __syncthreads();               // previous iter's LDS reads complete
    *(uint4*)&sA[idx0 * 8] = av0;
    *(uint4*)&sA[idx1 * 8] = av1;
    *(uint4*)&sB[idx0 * 8] = bv0;
    *(uint4*)&sB[idx1 * 8] = bv1;
    __syncthreads();               // LDS tile visible

    bf16x8 af[4], bfr[4];
#pragma unroll
    for (int mt = 0; mt < 4; mt++)
      af[mt]  = *(const bf16x8*)&sA[(wr * 64 + mt * 16 + lm) * 32 + q * 8];
#pragma unroll
    for (int nt = 0; nt < 4; nt++)
      bfr[nt] = *(const bf16x8*)&sB[(wc * 64 + nt * 16 + lm) * 32 + q * 8];

#pragma unroll
    for (int mt = 0; mt < 4; mt++)
#pragma unroll
      for (int nt = 0; nt < 4; nt++)
        acc[mt][nt] = __builtin_amdgcn_mfma_f32_16x16x32_bf16(
            af[mt], bfr[nt], acc[mt][nt], 0, 0, 0);
  }

  // ---- epilogue: transpose wave tile to row-major LDS (bias added) ----
  // C/D layout: col = nt*16+lm, row = mt*16+q*4+r  (m89/m91-verified)
  __syncthreads();                 // staging reads done; safe to reuse smem
  unsigned short* sT = smem + wave * 4096;    // 64x64 bf16 per wave
#pragma unroll
  for (int nt = 0; nt < 4; nt++) {
    const float bz = bias[bN + wc * 64 + nt * 16 + lm];
#pragma unroll
    for (int mt = 0; mt < 4; mt++)
#pragma unroll
      for (int r = 0; r < 4; r++)
        sT[(mt * 16 + q * 4 + r) * 64 + nt * 16 + lm] =
            f2bf(acc[mt][nt][r] + bz);
  }
  __syncthreads();

  // ---- lane n scans column n of this wave's chunk (zero init) ----
  const int gcol = bN + wc * 64 + lane;
  const float om  = TWO_PI_F * freq[gcol];
  const float osq = om * om;
  const float dp  = damp[gcol];
  float s = 0.f, v = 0.f;
#pragma unroll 8
  for (int i = 0; i < CL; i++) {
    float f = bf2f(sT[i * 64 + lane]);
    v += (-osq * s - dp * v + f) * DT;
    s += v * DT;
    sT[i * 64 + lane] = f2bf(s);   // in-place: zpart (columns disjoint/lane)
  }
  const int chunk = 2 * blockIdx.x + wr;
  chunkS[chunk * NDIM + gcol] = s;
  chunkV[chunk * NDIM + gcol] = v;
  __syncthreads();

  // ---- coalesced writeback of 64x64 bf16 zpart tile ----
#pragma unroll
  for (int k = 0; k < 8; k++) {
    int slot = lane + 64 * k;          // 0..511
    int row  = slot >> 3;              // 0..63
    int col8 = (slot & 7) * 8;
    *(uint4*)&zpart[(size_t)(bM + wr * 64 + row) * NDIM + bN + wc * 64 + col8] =
        *(uint4*)&sT[row * 64 + col8];
  }
}

// ======== kernel 2: lookback carry + homogeneous replay + osc/clip ========
// out[c*CL+i][n] = clip( (M^{i+1} carry_c).s + zpart[c*CL+i][n] + osc[n] )
// carry_c = sum_{cc<c} M64^{c-1-cc} partial_cc   (computed per block)
__global__ void scan_out_kernel(const unsigned short* __restrict__ zpart,
                                const float* __restrict__ amp,
                                const float* __restrict__ freq,
                                const float* __restrict__ phase,
                                const float* __restrict__ damp,
                                const float* __restrict__ chunkS,
                                const float* __restrict__ chunkV,
                                float* __restrict__ out) {
  int gid = blockIdx.x * blockDim.x + threadIdx.x;   // 0 .. CH*NDIM/4
  int n4 = gid & (NDIM / 4 - 1);
  int c  = gid >> 10;                                // / (NDIM/4)
  int n  = n4 * 4;

  float4 fr = *(const float4*)&freq[n];
  float4 dv = *(const float4*)&damp[n];
  float4 am = *(const float4*)&amp[n];
  float4 ph = *(const float4*)&phase[n];
  float omv[4] = {TWO_PI_F * fr.x, TWO_PI_F * fr.y, TWO_PI_F * fr.z, TWO_PI_F * fr.w};
  float dpv[4] = {dv.x, dv.y, dv.z, dv.w};
  float amv[4] = {am.x, am.y, am.z, am.w};
  float phv[4] = {ph.x, ph.y, ph.z, ph.w};
  float m00[4], m01[4], m10[4], m11[4];   // M per column
  float p00[4], p01[4], p10[4], p11[4];   // M^64 per column
  float osc[4];
#pragma unroll
  for (int j = 0; j < 4; j++) {
    float osq = omv[j] * omv[j];
    m00[j] = 1.f - osq * DT * DT;  m01[j] = DT * (1.f - dpv[j] * DT);
    m10[j] = -osq * DT;            m11[j] = 1.f - dpv[j] * DT;
    p00[j] = m00[j]; p01[j] = m01[j]; p10[j] = m10[j]; p11[j] = m11[j];
    osc[j] = amv[j] * sinf(omv[j] * DT + phv[j]);    // t = DT
  }
#pragma unroll
  for (int i = 0; i < 6; i++)                         // M^64 by squaring
#pragma unroll
    for (int j = 0; j < 4; j++) {
      float b00 = p00[j] * p00[j] + p01[j] * p10[j];
      float b01 = p00[j] * p01[j] + p01[j] * p11[j];
      float b10 = p10[j] * p00[j] + p11[j] * p10[j];
      float b11 = p10[j] * p01[j] + p11[j] * p11[j];
      p00[j] = b00; p01[j] = b01; p10[j] = b10; p11[j] = b11;
    }

  // lookback: carry entering chunk c
  float hs[4] = {0.f, 0.f, 0.f, 0.f}, hv[4] = {0.f, 0.f, 0.f, 0.f};
  for (int cc = 0; cc < c; cc++) {
    float4 ls = *(const float4*)&chunkS[cc * NDIM + n];
    float4 lv = *(const float4*)&chunkV[cc * NDIM + n];
    float lsv[4] = {ls.x, ls.y, ls.z, ls.w};
    float lvv[4] = {lv.x, lv.y, lv.z, lv.w};
#pragma unroll
    for (int j = 0; j < 4; j++) {
      float t = p00[j] * hs[j] + p01[j] * hv[j] + lsv[j];
      float u = p10[j] * hs[j] + p11[j] * hv[j] + lvv[j];
      hs[j] = t; hv[j] = u;
    }
  }

  // replay: homogeneous step + zpart + osc, clip, fp32 out
  const unsigned short* zp = zpart + (size_t)c * CL * NDIM + n;
  float* op = out + (size_t)c * CL * NDIM + n;
#pragma unroll 4
  for (int i = 0; i < CL; i++) {
    ushort4 zv = *(const ushort4*)&zp[(size_t)i * NDIM];
    float z[4] = {bf2f(zv.x), bf2f(zv.y), bf2f(zv.z), bf2f(zv.w)};
    float o[4];
#pragma unroll
    for (int j = 0; j < 4; j++) {
      float t = m00[j] * hs[j] + m01[j] * hv[j];     // h = M h  (M^{i+1} carry)
      float u = m10[j] * hs[j] + m11[j] * hv[j];
      hs[j] = t; hv[j] = u;
      o[j] = fminf(1.f, fmaxf(-1.f, hs[j] + z[j] + osc[j]));
    }
    *(float4*)&op[(size_t)i * NDIM] = (float4){o[0], o[1], o[2], o[3]};
  }
}

// ---------------- launch ----------------
extern "C" void kernel_launch(void* const* d_in, const int* in_sizes, int n_in,
                              void* d_out, int out_size, void* d_ws, size_t ws_size,
                              hipStream_t stream) {
  const float* x     = (const float*)d_in[0];
  const float* W     = (const float*)d_in[1];
  const float* bias  = (const float*)d_in[2];
  const float* amp   = (const float*)d_in[3];
  const float* freq  = (const float*)d_in[4];
  const float* phase = (const float*)d_in[5];
  const float* damp  = (const float*)d_in[6];

  // workspace: zpart bf16 32MB, chunkS/V 1MB each
  unsigned short* zpart = (unsigned short*)d_ws;
  float* chunkS = (float*)((char*)d_ws + (size_t)MDIM * NDIM * 2);
  float* chunkV = chunkS + CH * NDIM;

  dim3 gg(MDIM / 128, NDIM / 128);
  gemm_scan_kernel<<<gg, 256, 0, stream>>>(x, W, bias, freq, damp,
                                           zpart, chunkS, chunkV);

  scan_out_kernel<<<CH * NDIM / 4 / 256, 256, 0, stream>>>(
      zpart, amp, freq, phase, damp, chunkS, chunkV, (float*)d_out);
}